// Round 1
// baseline (118.859 us; speedup 1.0000x reference)
//
#include <hip/hip_runtime.h>
#include <math.h>

// ChamferDistance: B=4, N=M=8192, 3-D fp32 points.
// forward = mean_{b,i} sqrt(min_j ||s_i - t_j||^2 + EPS) * w[b,i]
// backward = mean_{b,j} sqrt(min_i ||...||^2 + EPS)
// out[0] = forward + backward
//
// Strategy: min over SQUARED distances (sqrt is monotone), with the
// ||q||^2 term factored out of the min:  d2 = qsq + min_r(rsq - 2 q.r).
// Two symmetric nearest-neighbor passes, atomicMin (uint bits of
// non-negative floats) into workspace, then 2-stage sum reduction.

#define EPS 1e-8f

constexpr int B_   = 4;
constexpr int N_   = 8192;   // source points per batch
constexpr int M_   = 8192;   // target points per batch
constexpr int TPB  = 256;    // threads per block
constexpr int QPT  = 4;      // query points per thread
constexpr int QT   = TPB * QPT;          // 1024 queries per block
constexpr int RCH  = 16;     // ref chunks (grid.y)
constexpr int CHUNK = N_ / RCH;          // 512 ref points staged per block
constexpr int RB   = 64;     // reduce-stage-1 blocks

// grid: (Nq/QT, RCH, B). Each block: QT queries vs one CHUNK of refs.
__global__ __launch_bounds__(TPB)
void nn_min_kernel(const float* __restrict__ qpts,   // (B, Nq, 3)
                   const float* __restrict__ rpts,   // (B, Nr, 3)
                   unsigned int* __restrict__ omin,  // (B*Nq) uint bits of min d2
                   int Nq, int Nr)
{
    __shared__ float4 sref[CHUNK];   // 8 KB: x,y,z,|r|^2
    const int b     = blockIdx.z;
    const int c     = blockIdx.y;
    const int qbase = blockIdx.x * QT;
    const int tid   = threadIdx.x;

    // stage ref chunk into LDS with precomputed |r|^2
    const int rbase = c * CHUNK;
    for (int k = tid; k < CHUNK; k += TPB) {
        const float* rp = rpts + ((size_t)b * Nr + rbase + k) * 3;
        float x = rp[0], y = rp[1], z = rp[2];
        sref[k] = make_float4(x, y, z, x * x + y * y + z * z);
    }

    // load this thread's queries into registers
    float qx[QPT], qy[QPT], qz[QPT], qs[QPT], mn[QPT];
#pragma unroll
    for (int qi = 0; qi < QPT; ++qi) {
        int i = qbase + qi * TPB + tid;
        const float* qp = qpts + ((size_t)b * Nq + i) * 3;
        float x = qp[0], y = qp[1], z = qp[2];
        qx[qi] = x; qy[qi] = y; qz[qi] = z;
        qs[qi] = x * x + y * y + z * z;
        mn[qi] = 3.0e38f;
    }
    __syncthreads();

    // inner loop: track min over refs of (|r|^2 - 2 q.r); unroll x2 -> v_min3
    for (int j = 0; j < CHUNK; j += 2) {
        float4 r0 = sref[j];
        float4 r1 = sref[j + 1];
#pragma unroll
        for (int qi = 0; qi < QPT; ++qi) {
            float t0 = fmaf(qz[qi], r0.z, fmaf(qy[qi], r0.y, qx[qi] * r0.x));
            float d0 = fmaf(-2.0f, t0, r0.w);
            float t1 = fmaf(qz[qi], r1.z, fmaf(qy[qi], r1.y, qx[qi] * r1.x));
            float d1 = fmaf(-2.0f, t1, r1.w);
            mn[qi] = fminf(mn[qi], fminf(d0, d1));
        }
    }

    // combine across ref chunks: atomicMin on uint bits (values >= 0)
#pragma unroll
    for (int qi = 0; qi < QPT; ++qi) {
        int i = qbase + qi * TPB + tid;
        float d2 = fmaxf(mn[qi] + qs[qi], 0.0f);   // guard tiny cancellation
        atomicMin(&omin[(size_t)b * Nq + i], __float_as_uint(d2));
    }
}

// stage 1: per-block partial sums of sqrt(min+EPS) with weights/means folded in
__global__ __launch_bounds__(TPB)
void reduce1_kernel(const unsigned int* __restrict__ minA,  // B*N
                    const unsigned int* __restrict__ minB,  // B*M
                    const float* __restrict__ w,            // B*N
                    float* __restrict__ bs)                 // RB partials
{
    const int BN = B_ * N_, BM = B_ * M_;
    const int total = BN + BM;
    const float invBN = 1.0f / (float)BN;
    const float invBM = 1.0f / (float)BM;

    float sum = 0.0f;
    for (int t = blockIdx.x * TPB + threadIdx.x; t < total; t += RB * TPB) {
        if (t < BN) {
            float m = __uint_as_float(minA[t]);
            sum += sqrtf(m + EPS) * w[t] * invBN;
        } else {
            float m = __uint_as_float(minB[t - BN]);
            sum += sqrtf(m + EPS) * invBM;
        }
    }

    __shared__ float ss[TPB / 64];
    int lane = threadIdx.x & 63;
    int wid  = threadIdx.x >> 6;
#pragma unroll
    for (int off = 32; off > 0; off >>= 1) sum += __shfl_down(sum, off);
    if (lane == 0) ss[wid] = sum;
    __syncthreads();
    if (threadIdx.x == 0) {
        float s = 0.0f;
#pragma unroll
        for (int i = 0; i < TPB / 64; ++i) s += ss[i];
        bs[blockIdx.x] = s;
    }
}

// stage 2: one wave sums the RB partials
__global__ __launch_bounds__(64)
void reduce2_kernel(const float* __restrict__ bs, float* __restrict__ out)
{
    float s = bs[threadIdx.x];   // RB == 64
#pragma unroll
    for (int off = 32; off > 0; off >>= 1) s += __shfl_down(s, off);
    if (threadIdx.x == 0) out[0] = s;
}

extern "C" void kernel_launch(void* const* d_in, const int* in_sizes, int n_in,
                              void* d_out, int out_size, void* d_ws, size_t ws_size,
                              hipStream_t stream)
{
    const float* src = (const float*)d_in[0];   // (B, N, 3)
    const float* tgt = (const float*)d_in[1];   // (B, M, 3)
    const float* w   = (const float*)d_in[2];   // (B, N)
    float* out = (float*)d_out;

    unsigned int* minA = (unsigned int*)d_ws;             // B*N
    unsigned int* minB = minA + (size_t)B_ * N_;          // B*M
    float* bs = (float*)(minB + (size_t)B_ * M_);         // RB floats

    // init mins to 0x7f7f7f7f (3.39e38 as float; uint order == float order for >=0)
    hipMemsetAsync(d_ws, 0x7f, (size_t)B_ * (N_ + M_) * sizeof(unsigned int), stream);

    dim3 gridA(N_ / QT, RCH, B_);   // 8 x 16 x 4 = 512 blocks
    nn_min_kernel<<<gridA, TPB, 0, stream>>>(src, tgt, minA, N_, M_);
    dim3 gridB(M_ / QT, RCH, B_);
    nn_min_kernel<<<gridB, TPB, 0, stream>>>(tgt, src, minB, M_, N_);

    reduce1_kernel<<<RB, TPB, 0, stream>>>(minA, minB, w, bs);
    reduce2_kernel<<<1, 64, 0, stream>>>(bs, out);
}

// Round 2
// 103.044 us; speedup vs baseline: 1.1535x; 1.1535x over previous
//
#include <hip/hip_runtime.h>
#include <math.h>

// ChamferDistance: B=4, N=M=8192, 3-D fp32 points.
// out[0] = mean_i sqrt(min_j d2)+w  +  mean_j sqrt(min_i d2)
// d2 = ||q||^2 + (||r||^2 - 2 q.r); min taken over the parenthesized term.
// LDS stores refs pre-scaled as (-2x,-2y,-2z,||r||^2) so the inner pair is
// exactly 3 FMA. Both NN directions fused in one kernel (grid.z = 2*B).
// Cross-chunk combine via atomicMin on uint bits (exact for floats >= 0).

#define EPS 1e-8f

constexpr int B_    = 4;
constexpr int N_    = 8192;            // points per batch (N == M)
constexpr int TPB   = 256;             // threads per block
constexpr int QPT   = 4;               // query points per thread
constexpr int QT    = TPB * QPT;       // 1024 queries per block
constexpr int RCH   = 32;              // ref chunks (grid.y)
constexpr int CHUNK = N_ / RCH;        // 256 ref points staged per block
constexpr int RB    = 64;              // reduce-stage-1 blocks

// grid: (N/QT=8, RCH=32, 2*B=8) = 2048 blocks -> 8 blocks/CU, 32 waves/CU.
__global__ __launch_bounds__(TPB)
void nn_min_kernel(const float* __restrict__ src,    // (B, N, 3)
                   const float* __restrict__ tgt,    // (B, N, 3)
                   unsigned int* __restrict__ minA,  // B*N  (src->tgt)
                   unsigned int* __restrict__ minB)  // B*N  (tgt->src)
{
    __shared__ float4 sref[CHUNK];   // 4 KB: (-2x, -2y, -2z, |r|^2)

    const int zb    = blockIdx.z;
    const int dir   = zb >> 2;           // 0: src queries tgt, 1: tgt queries src
    const int b     = zb & 3;
    const float*  qpts = dir ? tgt : src;
    const float*  rpts = dir ? src : tgt;
    unsigned int* omin = dir ? minB : minA;

    const int c     = blockIdx.y;
    const int qbase = blockIdx.x * QT;
    const int tid   = threadIdx.x;

    // stage ref chunk: one point per thread (CHUNK == TPB)
    {
        const float* rp = rpts + ((size_t)b * N_ + c * CHUNK + tid) * 3;
        float x = rp[0], y = rp[1], zz = rp[2];
        sref[tid] = make_float4(-2.0f * x, -2.0f * y, -2.0f * zz,
                                x * x + y * y + zz * zz);
    }

    // this thread's queries in registers
    float qx[QPT], qy[QPT], qz[QPT], qs[QPT], mn[QPT];
#pragma unroll
    for (int qi = 0; qi < QPT; ++qi) {
        int i = qbase + qi * TPB + tid;
        const float* qp = qpts + ((size_t)b * N_ + i) * 3;
        float x = qp[0], y = qp[1], zz = qp[2];
        qx[qi] = x; qy[qi] = y; qz[qi] = zz;
        qs[qi] = x * x + y * y + zz * zz;
        mn[qi] = 3.0e38f;
    }
    __syncthreads();

    // inner loop: 4 refs / iter, 3 FMA per pair, min3 folding
    for (int j = 0; j < CHUNK; j += 4) {
        float4 r0 = sref[j];
        float4 r1 = sref[j + 1];
        float4 r2 = sref[j + 2];
        float4 r3 = sref[j + 3];
#pragma unroll
        for (int qi = 0; qi < QPT; ++qi) {
            float d0 = fmaf(qx[qi], r0.x, fmaf(qy[qi], r0.y, fmaf(qz[qi], r0.z, r0.w)));
            float d1 = fmaf(qx[qi], r1.x, fmaf(qy[qi], r1.y, fmaf(qz[qi], r1.z, r1.w)));
            float d2 = fmaf(qx[qi], r2.x, fmaf(qy[qi], r2.y, fmaf(qz[qi], r2.z, r2.w)));
            float d3 = fmaf(qx[qi], r3.x, fmaf(qy[qi], r3.y, fmaf(qz[qi], r3.z, r3.w)));
            // nesting chosen to fold into two v_min3_f32
            mn[qi] = fminf(fminf(d0, d1), fminf(fminf(d2, d3), mn[qi]));
        }
    }

    // combine across ref chunks: atomicMin on uint bits (values >= 0)
#pragma unroll
    for (int qi = 0; qi < QPT; ++qi) {
        int i = qbase + qi * TPB + tid;
        float d2 = fmaxf(mn[qi] + qs[qi], 0.0f);   // guard tiny cancellation
        atomicMin(&omin[(size_t)b * N_ + i], __float_as_uint(d2));
    }
}

// stage 1: per-block partial sums of sqrt(min+EPS) with weights/means folded in
__global__ __launch_bounds__(TPB)
void reduce1_kernel(const unsigned int* __restrict__ minA,  // B*N
                    const unsigned int* __restrict__ minB,  // B*N
                    const float* __restrict__ w,            // B*N
                    float* __restrict__ bs)                 // RB partials
{
    const int BN = B_ * N_;
    const int total = 2 * BN;
    const float invBN = 1.0f / (float)BN;

    float sum = 0.0f;
    for (int t = blockIdx.x * TPB + threadIdx.x; t < total; t += RB * TPB) {
        if (t < BN) {
            float m = __uint_as_float(minA[t]);
            sum += sqrtf(m + EPS) * w[t] * invBN;
        } else {
            float m = __uint_as_float(minB[t - BN]);
            sum += sqrtf(m + EPS) * invBN;
        }
    }

    __shared__ float ss[TPB / 64];
    int lane = threadIdx.x & 63;
    int wid  = threadIdx.x >> 6;
#pragma unroll
    for (int off = 32; off > 0; off >>= 1) sum += __shfl_down(sum, off);
    if (lane == 0) ss[wid] = sum;
    __syncthreads();
    if (threadIdx.x == 0) {
        float s = 0.0f;
#pragma unroll
        for (int i = 0; i < TPB / 64; ++i) s += ss[i];
        bs[blockIdx.x] = s;
    }
}

// stage 2: one wave sums the RB partials
__global__ __launch_bounds__(64)
void reduce2_kernel(const float* __restrict__ bs, float* __restrict__ out)
{
    float s = bs[threadIdx.x];   // RB == 64
#pragma unroll
    for (int off = 32; off > 0; off >>= 1) s += __shfl_down(s, off);
    if (threadIdx.x == 0) out[0] = s;
}

extern "C" void kernel_launch(void* const* d_in, const int* in_sizes, int n_in,
                              void* d_out, int out_size, void* d_ws, size_t ws_size,
                              hipStream_t stream)
{
    const float* src = (const float*)d_in[0];   // (B, N, 3)
    const float* tgt = (const float*)d_in[1];   // (B, M, 3)
    const float* w   = (const float*)d_in[2];   // (B, N)
    float* out = (float*)d_out;

    unsigned int* minA = (unsigned int*)d_ws;             // B*N
    unsigned int* minB = minA + (size_t)B_ * N_;          // B*N
    float* bs = (float*)(minB + (size_t)B_ * N_);         // RB floats

    // init mins to 0x7f7f7f7f (3.39e38; uint order == float order for >= 0)
    hipMemsetAsync(d_ws, 0x7f, (size_t)2 * B_ * N_ * sizeof(unsigned int), stream);

    dim3 grid(N_ / QT, RCH, 2 * B_);   // 8 x 32 x 8 = 2048 blocks
    nn_min_kernel<<<grid, TPB, 0, stream>>>(src, tgt, minA, minB);

    reduce1_kernel<<<RB, TPB, 0, stream>>>(minA, minB, w, bs);
    reduce2_kernel<<<1, 64, 0, stream>>>(bs, out);
}